// Round 2
// baseline (128.203 us; speedup 1.0000x reference)
//
#include <hip/hip_runtime.h>
#include <hip/hip_bf16.h>

// DirectEncodingModel via MFMA. Per group, (16 rows x 24) @ (24x16) is ONE
// v_mfma_f32_16x16x32_bf16 (K padded 24->32; bias rides in k=24 against a
// pad column fixed to 1.0). Block = 1024 thr (16 waves) owns a 16-row acc
// tile in dynamic LDS; wave w does 4 groups/layer.
// R7: acc row stride 3588 u16 (=1794 dw == 2 mod 32); persistent blocks:
// grid=256 (1/CU), 4 tiles each; next tile's x prefetched into VGPRs by
// waves 8-15 during the head, dumped to LDS at the tile boundary.
// R9: (a) OPERAND SWAP: mfma(bfr, af) computes h^T = W^T * acc^T. A-frag
// [m=lane&15][k] and B-frag [k][n=lane&15] share the same lane mapping, so
// both existing fragments are reused unchanged. D now gives each lane 4
// CONSECUTIVE features of its own batch row nn -> C-write is ONE
// ds_write_b64 (was 4x ds_write_u16); head store is ONE dwordx4 (was 4x
// dword). (b) offset tables read straight from GLOBAL (L2-hot, VMEM pipe)
// instead of LDS: removes 8 ds_read_b128/wave/layer from the overloaded
// LDS pipe + kills the 25.6 KB staging. LDS instr/wave/layer: 56 -> 36.
// Layouts (HW-verified): A[m=lane&15][k=(lane>>4)*8+j];
//   B[k=(lane>>4)*8+j][n=lane&15]; C/D col=lane&15, row=(lane>>4)*4+reg.

typedef unsigned short ushort_t;
typedef unsigned int uint_t;
typedef __attribute__((ext_vector_type(8))) short short8;   // 8 bf16 frag
typedef __attribute__((ext_vector_type(4))) float f32x4;    // MFMA acc

#define ACC_STRIDE 3588                   // u16 per row; 7176 B = 1794 dw == 2 mod 32
#define ROW_BYTES (ACC_STRIDE * 2)
#define PAD_ONE 3584                      // pad col holding bf16 1.0
#define ONE_BYTE (PAD_ONE * 2)            // 7168
#define ZERO_BYTE (3586 * 2)              // 7172 (col 3586 == 0)
#define ACC_U16 (16 * ACC_STRIDE)         // 57408 u16 = 114816 B
#define LDS_BYTES (ACC_U16 * 2)           // 114816 B (offsets no longer staged)

// d_ws layout (bytes)
#define OFF_HID_B 204800                  // after 12800 frags * 16 B
#define OFF_HEAD_B 229376                 // + 6144 * 4

__device__ __forceinline__ ushort_t f2bf(float f) {
    __hip_bfloat16 h = __float2bfloat16(f);
    union { __hip_bfloat16 h; ushort_t u; } v;
    v.h = h;
    return v.u;
}

__device__ __forceinline__ uint_t pack2bf(float lo, float hi) {
    return (uint_t)f2bf(lo) | ((uint_t)f2bf(hi) << 16);
}

// tanh(x) = 1 - 2/(e^2x + 1); exp saturation gives exact +-1 tails, no clamp.
__device__ __forceinline__ float fast_tanh(float x) {
    float e = __expf(2.0f * x);
    return fmaf(-2.0f, __builtin_amdgcn_rcpf(e + 1.0f), 1.0f);
}

// ---- Pre-pack weights (B-frag order, bias in k=24/k=48 slot) + offsets ----
__global__ __launch_bounds__(256)
void convert_weights(const float* __restrict__ W1, const float* __restrict__ b1,
                     const float* __restrict__ W2, const float* __restrict__ b2,
                     const float* __restrict__ W3, const float* __restrict__ b3,
                     const float* __restrict__ Wo, const float* __restrict__ bo,
                     const int* __restrict__ idx1, const int* __restrict__ idx2,
                     const int* __restrict__ idx3, const int* __restrict__ idxo,
                     ushort_t* __restrict__ ws)
{
    const int tid = blockIdx.x * 256 + threadIdx.x;
    const int lane = tid & 63;
    const int nn = lane & 15;
    const int quad = lane >> 4;
    if (tid < 12288) {
        const int g = (tid >> 6) & 63;
        const int l = tid >> 12;   // 0..2
        const float* W = (l == 0) ? W1 : (l == 1) ? W2 : W3;
        const float* bb = (l == 0) ? b1 : (l == 1) ? b2 : b3;
        const float* Wg = W + g * 384;
        ushort_t v[8];
        #pragma unroll
        for (int j = 0; j < 8; ++j) {
            const int k = quad * 8 + j;
            v[j] = (k < 24) ? f2bf(Wg[k * 16 + nn])
                 : (k == 24) ? f2bf(bb[g * 16 + nn]) : (ushort_t)0;
        }
        ushort4* dst = reinterpret_cast<ushort4*>(ws + (size_t)tid * 8);
        dst[0] = make_ushort4(v[0], v[1], v[2], v[3]);
        dst[1] = make_ushort4(v[4], v[5], v[6], v[7]);
    } else if (tid < 12800) {
        const int h = tid - 12288;
        const int gs = h >> 6;          // 0..7: go*2+step
        const int go = gs >> 1;
        const int step = gs & 1;
        const float* Wg = Wo + go * 768;
        ushort_t v[8];
        #pragma unroll
        for (int j = 0; j < 8; ++j) {
            const int k = step * 32 + quad * 8 + j;
            v[j] = (k < 48) ? f2bf(Wg[k * 16 + nn])
                 : (k == 48) ? f2bf(bo[go * 16 + nn]) : (ushort_t)0;
        }
        ushort4* dst = reinterpret_cast<ushort4*>(ws + (size_t)tid * 8);
        dst[0] = make_ushort4(v[0], v[1], v[2], v[3]);
        dst[1] = make_ushort4(v[4], v[5], v[6], v[7]);
    } else if (tid < 18944) {
        // hidden gather byte-offsets, frag order: e = l*2048 + g*32 + k
        const int e = tid - 12800;
        const int l = e >> 11;
        const int rem = e & 2047;
        const int g = rem >> 5;
        const int k = rem & 31;
        const int* idx = (l == 0) ? idx1 : (l == 1) ? idx2 : idx3;
        const int v = (k < 24) ? idx[g * 24 + k] * 2
                    : (k == 24) ? ONE_BYTE : ZERO_BYTE;
        reinterpret_cast<int*>((char*)ws + OFF_HID_B)[e] = v;
    } else if (tid < 19200) {
        // head gather byte-offsets: e = go*64 + k
        const int e = tid - 18944;
        const int go = e >> 6;
        const int k = e & 63;
        const int v = (k < 48) ? idxo[go * 48 + k] * 2
                    : (k == 48) ? ONE_BYTE : ZERO_BYTE;
        reinterpret_cast<int*>((char*)ws + OFF_HEAD_B)[e] = v;
    }
}

#define NTILES 4   // 16384 rows / 16 per tile / 256 blocks

__global__ __launch_bounds__(1024)
void demodel_mfma(const float* __restrict__ x,
                  const ushort_t* __restrict__ ws,
                  float* __restrict__ out)
{
    extern __shared__ __align__(16) ushort_t smem[];
    const int t = threadIdx.x;
    const int lane = t & 63;
    const int wv = t >> 6;               // wave 0..15
    const int nn = lane & 15;
    const int quad = lane >> 4;

    // offset tables live in GLOBAL (L2-hot; VMEM pipe, off the LDS pipe)
    const int* offs = reinterpret_cast<const int*>((const char*)ws + OFF_HID_B);

    // pad cols per row: [3584]=1.0 (bias slot), [3585..3587]=0  (8 B, b64)
    if (t < 16) {
        uint2* p = reinterpret_cast<uint2*>((char*)smem + t * ROW_BYTES + ONE_BYTE);
        *p = make_uint2(0x00003f80u, 0u);
    }

    const char* accb = (const char*)smem + nn * ROW_BYTES;   // lane's row nn
    char* accw = (char*)smem;

    // prefetch regs for the x tile (waves 8..15: 512 thr x 16 floats)
    const int pr = (t - 512) >> 5;        // row 0..15 (valid for wv>=8)
    const int pc = (t & 31) << 4;         // float col 0..496
    uint_t px[8];

    // ---- prefetch tile 0 ----
    if (wv >= 8) {
        const float4* src = reinterpret_cast<const float4*>(
            x + ((size_t)blockIdx.x * 16 + pr) * 512 + pc);
        float4 a0 = src[0], a1 = src[1], a2 = src[2], a3 = src[3];
        px[0] = pack2bf(a0.x, a0.y); px[1] = pack2bf(a0.z, a0.w);
        px[2] = pack2bf(a1.x, a1.y); px[3] = pack2bf(a1.z, a1.w);
        px[4] = pack2bf(a2.x, a2.y); px[5] = pack2bf(a2.z, a2.w);
        px[6] = pack2bf(a3.x, a3.y); px[7] = pack2bf(a3.z, a3.w);
    }

    #pragma unroll 1
    for (int it = 0; it < NTILES; ++it) {
        const int row0 = (it * 256 + blockIdx.x) * 16;

        __syncthreads();   // prev tile's head gathers done -> x region free
        if (wv >= 8) {     // dump prefetched x: 16 u16 = 32 B as 4x b64
            uint2* d = reinterpret_cast<uint2*>(accw + pr * ROW_BYTES + pc * 2);
            d[0] = make_uint2(px[0], px[1]);
            d[1] = make_uint2(px[2], px[3]);
            d[2] = make_uint2(px[4], px[5]);
            d[3] = make_uint2(px[6], px[7]);
        }
        __syncthreads();

        // ---- 3 hidden layers ----
        #pragma unroll 1
        for (int l = 0; l < 3; ++l) {
            const int out_base = 512 + l * 1024;
            const int g0 = wv << 2;

            int4 o0[4], o1[4];
            short8 bfr[4];
            #pragma unroll
            for (int gi = 0; gi < 4; ++gi) {
                const int* op = offs + l * 2048 + (g0 + gi) * 32 + quad * 8;
                o0[gi] = *reinterpret_cast<const int4*>(op);
                o1[gi] = *reinterpret_cast<const int4*>(op + 4);
                bfr[gi] = *reinterpret_cast<const short8*>(
                    ws + (((size_t)l * 64 + g0 + gi) * 64 + lane) * 8);
            }

            short8 af[4];
            #pragma unroll
            for (int gi = 0; gi < 4; ++gi) {
                af[gi][0] = *(const short*)(accb + o0[gi].x);
                af[gi][1] = *(const short*)(accb + o0[gi].y);
                af[gi][2] = *(const short*)(accb + o0[gi].z);
                af[gi][3] = *(const short*)(accb + o0[gi].w);
                af[gi][4] = *(const short*)(accb + o1[gi].x);
                af[gi][5] = *(const short*)(accb + o1[gi].y);
                af[gi][6] = *(const short*)(accb + o1[gi].z);
                af[gi][7] = *(const short*)(accb + o1[gi].w);
            }

            f32x4 acc[4];
            #pragma unroll
            for (int gi = 0; gi < 4; ++gi) {
                f32x4 z = { 0.f, 0.f, 0.f, 0.f };
                // swapped: D = W^T * acc^T; lane holds 4 consecutive
                // features (quad*4+i) of its own batch row nn
                acc[gi] = __builtin_amdgcn_mfma_f32_16x16x32_bf16(bfr[gi], af[gi], z, 0, 0, 0);
            }

            #pragma unroll
            for (int gi = 0; gi < 4; ++gi) {
                const int colo = out_base + (g0 + gi) * 16 + quad * 4;
                uint2 w = make_uint2(
                    pack2bf(fast_tanh(acc[gi][0]), fast_tanh(acc[gi][1])),
                    pack2bf(fast_tanh(acc[gi][2]), fast_tanh(acc[gi][3])));
                *reinterpret_cast<uint2*>(accw + nn * ROW_BYTES + colo * 2) = w;
            }
            __syncthreads();
        }

        // ---- head (waves 0..3) and next-x prefetch (waves 8..15) ----
        if (wv < 4) {
            const int go = wv;
            int4 o0[2], o1[2];
            short8 bfr[2];
            #pragma unroll
            for (int s = 0; s < 2; ++s) {
                const int* op = offs + 6144 + go * 64 + s * 32 + quad * 8;
                o0[s] = *reinterpret_cast<const int4*>(op);
                o1[s] = *reinterpret_cast<const int4*>(op + 4);
                bfr[s] = *reinterpret_cast<const short8*>(
                    ws + (12288 + ((size_t)go * 2 + s) * 64 + lane) * 8);
            }
            short8 af[2];
            #pragma unroll
            for (int s = 0; s < 2; ++s) {
                af[s][0] = *(const short*)(accb + o0[s].x);
                af[s][1] = *(const short*)(accb + o0[s].y);
                af[s][2] = *(const short*)(accb + o0[s].z);
                af[s][3] = *(const short*)(accb + o0[s].w);
                af[s][4] = *(const short*)(accb + o1[s].x);
                af[s][5] = *(const short*)(accb + o1[s].y);
                af[s][6] = *(const short*)(accb + o1[s].z);
                af[s][7] = *(const short*)(accb + o1[s].w);
            }
            f32x4 z = { 0.f, 0.f, 0.f, 0.f };
            f32x4 a0 = __builtin_amdgcn_mfma_f32_16x16x32_bf16(bfr[0], af[0], z, 0, 0, 0);
            f32x4 a1 = __builtin_amdgcn_mfma_f32_16x16x32_bf16(bfr[1], af[1], z, 0, 0, 0);
            // lane holds out[row0+nn][go*16 + quad*4 .. +3] -> one dwordx4
            float4 o;
            o.x = a0[0] + a1[0];
            o.y = a0[1] + a1[1];
            o.z = a0[2] + a1[2];
            o.w = a0[3] + a1[3];
            *reinterpret_cast<float4*>(
                out + (size_t)(row0 + nn) * 64 + go * 16 + quad * 4) = o;
        }
        if (wv >= 8 && it + 1 < NTILES) {
            const float4* src = reinterpret_cast<const float4*>(
                x + (((size_t)(it + 1) * 256 + blockIdx.x) * 16 + pr) * 512 + pc);
            float4 a0 = src[0], a1 = src[1], a2 = src[2], a3 = src[3];
            px[0] = pack2bf(a0.x, a0.y); px[1] = pack2bf(a0.z, a0.w);
            px[2] = pack2bf(a1.x, a1.y); px[3] = pack2bf(a1.z, a1.w);
            px[4] = pack2bf(a2.x, a2.y); px[5] = pack2bf(a2.z, a2.w);
            px[6] = pack2bf(a3.x, a3.y); px[7] = pack2bf(a3.z, a3.w);
        }
    }
}

extern "C" void kernel_launch(void* const* d_in, const int* in_sizes, int n_in,
                              void* d_out, int out_size, void* d_ws, size_t ws_size,
                              hipStream_t stream) {
    const float* x  = (const float*)d_in[0];
    const float* W1 = (const float*)d_in[1];
    const float* b1 = (const float*)d_in[2];
    const float* W2 = (const float*)d_in[3];
    const float* b2 = (const float*)d_in[4];
    const float* W3 = (const float*)d_in[5];
    const float* b3 = (const float*)d_in[6];
    const float* Wo = (const float*)d_in[7];
    const float* bo = (const float*)d_in[8];
    const int* idx1 = (const int*)d_in[9];
    const int* idx2 = (const int*)d_in[10];
    const int* idx3 = (const int*)d_in[11];
    const int* idxo = (const int*)d_in[12];
    float* out = (float*)d_out;

    (void)hipFuncSetAttribute((const void*)demodel_mfma,
                              hipFuncAttributeMaxDynamicSharedMemorySize,
                              LDS_BYTES);

    convert_weights<<<75, 256, 0, stream>>>(W1, b1, W2, b2, W3, b3, Wo, bo,
                                            idx1, idx2, idx3, idxo,
                                            (ushort_t*)d_ws);

    demodel_mfma<<<256, 1024, LDS_BYTES, stream>>>(
        x, (const ushort_t*)d_ws, out);
}

// Round 3
// 127.052 us; speedup vs baseline: 1.0091x; 1.0091x over previous
//
#include <hip/hip_runtime.h>
#include <hip/hip_bf16.h>

// DirectEncodingModel via MFMA, SINGLE kernel, ZERO workspace (R10).
// Per group, (16 rows x 24) @ (24x16) is ONE v_mfma_f32_16x16x32_bf16
// (K padded 24->32; bias rides at k=24 against a pad column fixed to 1.0).
// Block = 1024 thr (16 waves) owns a 16-row acc tile in dynamic LDS.
// R7: acc row stride 3588 u16 (7176 B, 1794 dw == 2 mod 32); persistent
// blocks grid=256 (1/CU), 4 tiles each; next x tile prefetched into VGPRs
// by waves 8-15 during the head, dumped to LDS at the tile boundary.
// R9 (kept): operand swap mfma(W, af) -> D = h^T: lane holds 4 CONSECUTIVE
// features of its own batch row nn -> C-write is one uint2, head store one
// float4 (coalesced).
// R10: d_ws eliminated. Theory: the ~43us x2 fillBufferAligned (256 MiB
// workspace poison) dispatches dominate dur_us (~86 of 123 us); kernel is
// ~33 us. Weights converted inline ONCE per block into 12+2 resident
// short8 frags (quad<3: 8 strided W floats; quad==3: bias at j=0). Offset
// tables computed inline from idx* into the R0-R8 LDS layout (broadcast
// ds_read_b128 -- R9's per-layer L2 offset loads were the regression).
// Hot loop uses R8's 2-group halves (peak VGPR ~120 with 56 resident
// weight regs) with sched_barrier(0) between halves.
// Layouts (HW-verified): A[m=lane&15][k=(lane>>4)*8+j];
//   B[k=(lane>>4)*8+j][n=lane&15]; C/D col=lane&15, row=(lane>>4)*4+reg.

typedef unsigned short ushort_t;
typedef unsigned int uint_t;
typedef __attribute__((ext_vector_type(8))) short short8;   // 8 bf16 frag
typedef __attribute__((ext_vector_type(4))) float f32x4;    // MFMA acc

#define ACC_STRIDE 3588                   // u16 per row; 7176 B = 1794 dw == 2 mod 32
#define ROW_BYTES (ACC_STRIDE * 2)
#define PAD_ONE 3584                      // pad col holding bf16 1.0
#define ONE_BYTE (PAD_ONE * 2)            // 7168
#define ZERO_BYTE (3586 * 2)              // 7172 (col 3586 == 0)
#define ACC_U16 (16 * ACC_STRIDE)         // 57408 u16 = 114816 B
#define OFFS_INTS 6400                    // hidden 6144 + head 256
#define LDS_BYTES (ACC_U16 * 2 + OFFS_INTS * 4)   // 140416 B

__device__ __forceinline__ ushort_t f2bf(float f) {
    __hip_bfloat16 h = __float2bfloat16(f);
    union { __hip_bfloat16 h; ushort_t u; } v;
    v.h = h;
    return v.u;
}

__device__ __forceinline__ uint_t pack2bf(float lo, float hi) {
    return (uint_t)f2bf(lo) | ((uint_t)f2bf(hi) << 16);
}

// tanh(x) = 1 - 2/(e^2x + 1); exp saturation gives exact +-1 tails, no clamp.
__device__ __forceinline__ float fast_tanh(float x) {
    float e = __expf(2.0f * x);
    return fmaf(-2.0f, __builtin_amdgcn_rcpf(e + 1.0f), 1.0f);
}

#define NTILES 4   // 16384 rows / 16 per tile / 256 blocks

__global__ __launch_bounds__(1024)
void demodel_mfma(const float* __restrict__ x,
                  const float* __restrict__ W1, const float* __restrict__ b1,
                  const float* __restrict__ W2, const float* __restrict__ b2,
                  const float* __restrict__ W3, const float* __restrict__ b3,
                  const float* __restrict__ Wo, const float* __restrict__ bo,
                  const int* __restrict__ idx1, const int* __restrict__ idx2,
                  const int* __restrict__ idx3, const int* __restrict__ idxo,
                  float* __restrict__ out)
{
    extern __shared__ __align__(16) ushort_t smem[];
    const int t = threadIdx.x;
    const int lane = t & 63;
    const int wv = t >> 6;               // wave 0..15
    const int nn = lane & 15;
    const int quad = lane >> 4;

    // prefetch regs for the x tile (waves 8..15: 512 thr x 16 floats)
    const int pr = (t - 512) >> 5;        // row 0..15 (valid for wv>=8)
    const int pc = (t & 31) << 4;         // float col 0..496
    uint_t px[8];

    // ---- issue tile-0 x prefetch first (longest latency) ----
    if (wv >= 8) {
        const float4* src = reinterpret_cast<const float4*>(
            x + ((size_t)blockIdx.x * 16 + pr) * 512 + pc);
        float4 a0 = src[0], a1 = src[1], a2 = src[2], a3 = src[3];
        px[0] = pack2bf(a0.x, a0.y); px[1] = pack2bf(a0.z, a0.w);
        px[2] = pack2bf(a1.x, a1.y); px[3] = pack2bf(a1.z, a1.w);
        px[4] = pack2bf(a2.x, a2.y); px[5] = pack2bf(a2.z, a2.w);
        px[6] = pack2bf(a3.x, a3.y); px[7] = pack2bf(a3.z, a3.w);
    }

    // ---- offset tables: computed inline from idx*, staged to LDS ----
    // hidden: e = l*2048 + g*32 + k ; head: 6144 + go*64 + k
    int* offs_w = reinterpret_cast<int*>(smem + ACC_U16);
    for (int e = t; e < OFFS_INTS; e += 1024) {
        int v;
        if (e < 6144) {
            const int l = e >> 11;
            const int rem = e & 2047;
            const int g = rem >> 5;
            const int k = rem & 31;
            const int* idx = (l == 0) ? idx1 : (l == 1) ? idx2 : idx3;
            v = (k < 24) ? idx[g * 24 + k] * 2
              : (k == 24) ? ONE_BYTE : ZERO_BYTE;
        } else {
            const int e2 = e - 6144;
            const int go = e2 >> 6;
            const int k = e2 & 63;
            v = (k < 48) ? idxo[go * 48 + k] * 2
              : (k == 48) ? ONE_BYTE : ZERO_BYTE;
        }
        offs_w[e] = v;
    }

    // pad cols per row: [3584]=1.0 (bias slot), [3585..3587]=0  (8 B)
    if (t < 16) {
        uint2* p = reinterpret_cast<uint2*>((char*)smem + t * ROW_BYTES + ONE_BYTE);
        *p = make_uint2(0x00003f80u, 0u);
    }

    // ---- hoist weight conversion: 12 resident hidden frags ----
    // frag(l,g): quad<3 -> 8 strided W floats; quad==3 -> bias at j=0.
    short8 wfr[12];
    #pragma unroll
    for (int l = 0; l < 3; ++l) {
        const float* W = (l == 0) ? W1 : (l == 1) ? W2 : W3;
        const float* bb = (l == 0) ? b1 : (l == 1) ? b2 : b3;
        #pragma unroll
        for (int u = 0; u < 4; ++u) {
            const int g = (wv << 2) + u;
            short8 v;
            if (quad < 3) {
                const float* p = W + g * 384 + (quad * 8) * 16 + nn;
                #pragma unroll
                for (int j = 0; j < 8; ++j) v[j] = (short)f2bf(p[j * 16]);
            } else {
                #pragma unroll
                for (int j = 0; j < 8; ++j) v[j] = 0;
                v[0] = (short)f2bf(bb[g * 16 + nn]);
            }
            wfr[l * 4 + u] = v;
        }
    }
    // head frags (waves 0..3): K=64 in two steps; k = s*32 + quad*8 + j
    short8 hwf[2];
    if (wv < 4) {
        #pragma unroll
        for (int s = 0; s < 2; ++s) {
            const int k0 = s * 32 + quad * 8;
            short8 v;
            if (k0 < 48) {
                const float* p = Wo + wv * 768 + k0 * 16 + nn;
                #pragma unroll
                for (int j = 0; j < 8; ++j) v[j] = (short)f2bf(p[j * 16]);
            } else if (k0 == 48) {
                #pragma unroll
                for (int j = 0; j < 8; ++j) v[j] = 0;
                v[0] = (short)f2bf(bo[wv * 16 + nn]);
            } else {
                #pragma unroll
                for (int j = 0; j < 8; ++j) v[j] = 0;
            }
            hwf[s] = v;
        }
    }

    const int* offs = offs_w;
    const char* accb = (const char*)smem + nn * ROW_BYTES;   // lane's row nn
    char* accw = (char*)smem;

// one 2-group half-layer; L, HB are literal constants (static wfr index)
#define HALF_LAYER(L, HB)                                                   \
    {                                                                       \
        const int g0 = (wv << 2) + ((HB) << 1);                             \
        int4 o0[2], o1[2];                                                  \
        _Pragma("unroll")                                                   \
        for (int gi = 0; gi < 2; ++gi) {                                    \
            const int* op = offs + (L) * 2048 + (g0 + gi) * 32 + quad * 8;  \
            o0[gi] = *reinterpret_cast<const int4*>(op);                    \
            o1[gi] = *reinterpret_cast<const int4*>(op + 4);                \
        }                                                                   \
        short8 af[2];                                                       \
        _Pragma("unroll")                                                   \
        for (int gi = 0; gi < 2; ++gi) {                                    \
            af[gi][0] = *(const short*)(accb + o0[gi].x);                   \
            af[gi][1] = *(const short*)(accb + o0[gi].y);                   \
            af[gi][2] = *(const short*)(accb + o0[gi].z);                   \
            af[gi][3] = *(const short*)(accb + o0[gi].w);                   \
            af[gi][4] = *(const short*)(accb + o1[gi].x);                   \
            af[gi][5] = *(const short*)(accb + o1[gi].y);                   \
            af[gi][6] = *(const short*)(accb + o1[gi].z);                   \
            af[gi][7] = *(const short*)(accb + o1[gi].w);                   \
        }                                                                   \
        f32x4 acc[2];                                                       \
        _Pragma("unroll")                                                   \
        for (int gi = 0; gi < 2; ++gi) {                                    \
            f32x4 z = { 0.f, 0.f, 0.f, 0.f };                               \
            acc[gi] = __builtin_amdgcn_mfma_f32_16x16x32_bf16(              \
                wfr[(L) * 4 + (HB) * 2 + gi], af[gi], z, 0, 0, 0);          \
        }                                                                   \
        _Pragma("unroll")                                                   \
        for (int gi = 0; gi < 2; ++gi) {                                    \
            const int colo = 512 + (L) * 1024 + (g0 + gi) * 16 + quad * 4;  \
            uint2 w = make_uint2(                                           \
                pack2bf(fast_tanh(acc[gi][0]), fast_tanh(acc[gi][1])),      \
                pack2bf(fast_tanh(acc[gi][2]), fast_tanh(acc[gi][3])));     \
            *reinterpret_cast<uint2*>(accw + nn * ROW_BYTES + colo * 2) = w;\
        }                                                                   \
    }

#define LAYER(L)                                                            \
    HALF_LAYER(L, 0)                                                        \
    __builtin_amdgcn_sched_barrier(0);                                      \
    HALF_LAYER(L, 1)                                                        \
    __syncthreads();

    #pragma unroll 1
    for (int it = 0; it < NTILES; ++it) {
        const int row0 = (it * 256 + blockIdx.x) * 16;

        __syncthreads();   // prev tile's head gathers done -> x region free
        if (wv >= 8) {     // dump prefetched x: 16 u16 = 32 B as 4x b64
            uint2* d = reinterpret_cast<uint2*>(accw + pr * ROW_BYTES + pc * 2);
            d[0] = make_uint2(px[0], px[1]);
            d[1] = make_uint2(px[2], px[3]);
            d[2] = make_uint2(px[4], px[5]);
            d[3] = make_uint2(px[6], px[7]);
        }
        __syncthreads();

        LAYER(0)
        LAYER(1)
        LAYER(2)

        // ---- head (waves 0..3) and next-x prefetch (waves 8..15) ----
        if (wv < 4) {
            const int go = wv;
            int4 o0[2], o1[2];
            #pragma unroll
            for (int s = 0; s < 2; ++s) {
                const int* op = offs + 6144 + go * 64 + s * 32 + quad * 8;
                o0[s] = *reinterpret_cast<const int4*>(op);
                o1[s] = *reinterpret_cast<const int4*>(op + 4);
            }
            short8 af[2];
            #pragma unroll
            for (int s = 0; s < 2; ++s) {
                af[s][0] = *(const short*)(accb + o0[s].x);
                af[s][1] = *(const short*)(accb + o0[s].y);
                af[s][2] = *(const short*)(accb + o0[s].z);
                af[s][3] = *(const short*)(accb + o0[s].w);
                af[s][4] = *(const short*)(accb + o1[s].x);
                af[s][5] = *(const short*)(accb + o1[s].y);
                af[s][6] = *(const short*)(accb + o1[s].z);
                af[s][7] = *(const short*)(accb + o1[s].w);
            }
            f32x4 z = { 0.f, 0.f, 0.f, 0.f };
            f32x4 a0 = __builtin_amdgcn_mfma_f32_16x16x32_bf16(hwf[0], af[0], z, 0, 0, 0);
            f32x4 a1 = __builtin_amdgcn_mfma_f32_16x16x32_bf16(hwf[1], af[1], z, 0, 0, 0);
            // lane holds out[row0+nn][go*16 + quad*4 .. +3] -> one dwordx4
            float4 o;
            o.x = a0[0] + a1[0];
            o.y = a0[1] + a1[1];
            o.z = a0[2] + a1[2];
            o.w = a0[3] + a1[3];
            *reinterpret_cast<float4*>(
                out + (size_t)(row0 + nn) * 64 + go * 16 + quad * 4) = o;
        }
        if (wv >= 8 && it + 1 < NTILES) {
            const float4* src = reinterpret_cast<const float4*>(
                x + (((size_t)(it + 1) * 256 + blockIdx.x) * 16 + pr) * 512 + pc);
            float4 a0 = src[0], a1 = src[1], a2 = src[2], a3 = src[3];
            px[0] = pack2bf(a0.x, a0.y); px[1] = pack2bf(a0.z, a0.w);
            px[2] = pack2bf(a1.x, a1.y); px[3] = pack2bf(a1.z, a1.w);
            px[4] = pack2bf(a2.x, a2.y); px[5] = pack2bf(a2.z, a2.w);
            px[6] = pack2bf(a3.x, a3.y); px[7] = pack2bf(a3.z, a3.w);
        }
    }
#undef LAYER
#undef HALF_LAYER
}

extern "C" void kernel_launch(void* const* d_in, const int* in_sizes, int n_in,
                              void* d_out, int out_size, void* d_ws, size_t ws_size,
                              hipStream_t stream) {
    const float* x  = (const float*)d_in[0];
    const float* W1 = (const float*)d_in[1];
    const float* b1 = (const float*)d_in[2];
    const float* W2 = (const float*)d_in[3];
    const float* b2 = (const float*)d_in[4];
    const float* W3 = (const float*)d_in[5];
    const float* b3 = (const float*)d_in[6];
    const float* Wo = (const float*)d_in[7];
    const float* bo = (const float*)d_in[8];
    const int* idx1 = (const int*)d_in[9];
    const int* idx2 = (const int*)d_in[10];
    const int* idx3 = (const int*)d_in[11];
    const int* idxo = (const int*)d_in[12];
    float* out = (float*)d_out;
    (void)d_ws; (void)ws_size;   // workspace intentionally unused (R10)

    (void)hipFuncSetAttribute((const void*)demodel_mfma,
                              hipFuncAttributeMaxDynamicSharedMemorySize,
                              LDS_BYTES);

    demodel_mfma<<<256, 1024, LDS_BYTES, stream>>>(
        x, W1, b1, W2, b2, W3, b3, Wo, bo, idx1, idx2, idx3, idxo, out);
}

// Round 4
// 121.854 us; speedup vs baseline: 1.0521x; 1.0427x over previous
//
#include <hip/hip_runtime.h>
#include <hip/hip_bf16.h>

// DirectEncodingModel via MFMA. Per group, (16 rows x 24) @ (24x16) is ONE
// v_mfma_f32_16x16x32_bf16 (K padded 24->32; bias rides in k=24 against a
// pad column fixed to 1.0). Block = 1024 thr (16 waves) owns a 16-row acc
// tile in dynamic LDS; wave w does 4 groups/layer.
// R7: acc row stride 3588 u16 (7176 B, 1794 dw == 2 mod 32): each quad's
// 16 rows map to 16 distinct banks. Persistent blocks: grid=256 (1/CU),
// 4 tiles each; next x tile prefetched into VGPRs by waves 8-15 during
// the head, dumped to LDS at the tile boundary.
// R11: (a) REVERT to two-kernel prepass (R10's inline weight conversion
// was rematerialized into the loop by the compiler -- VGPR_Count=52 proved
// wfr never stayed resident; kernel 33->49us). The 2x256MiB ws poison
// (~87us) is unconditional & in the timed window (R0-R3 arithmetic), so
// d_ws use is free. (b) KEEP R9 operand swap: mfma(W, af) -> lane holds 4
// consecutive features of its own batch row nn -> C-write is one
// ds_write_b64 (was 4 scalar u16), head store one coalesced float4.
// (c) OFFSET TABLES PACKED u16 (max 7172 fits): per group, one
// ds_read_b128 yields 8 offsets (was 2x b128 of int32) -> offset LDS
// traffic halves; unpack = 1 extra VALU per gather addr (VALU at 37%,
// has headroom).
// Layouts (HW-verified): A[m=lane&15][k=(lane>>4)*8+j];
//   B[k=(lane>>4)*8+j][n=lane&15]; C/D col=lane&15, row=(lane>>4)*4+reg.

typedef unsigned short ushort_t;
typedef unsigned int uint_t;
typedef __attribute__((ext_vector_type(8))) short short8;   // 8 bf16 frag
typedef __attribute__((ext_vector_type(4))) float f32x4;    // MFMA acc

#define ACC_STRIDE 3588                   // u16 per row; 7176 B = 1794 dw == 2 mod 32
#define ROW_BYTES (ACC_STRIDE * 2)
#define PAD_ONE 3584                      // pad col holding bf16 1.0
#define ONE_BYTE (PAD_ONE * 2)            // 7168
#define ZERO_BYTE (3586 * 2)              // 7172 (col 3586 == 0)
#define ACC_U16 (16 * ACC_STRIDE)         // 57408 u16 = 114816 B
#define OFFS_U16 6400                     // hidden 6144 + head 256 (u16 each)
#define LDS_BYTES (ACC_U16 * 2 + OFFS_U16 * 2)   // 127616 B

// d_ws layout (bytes)
#define OFF_HIDO_B 204800                 // after 12800 frags * 16 B
#define OFF_HEADO_B (204800 + 12288)      // hidden offs 6144 * 2 B

__device__ __forceinline__ ushort_t f2bf(float f) {
    __hip_bfloat16 h = __float2bfloat16(f);
    union { __hip_bfloat16 h; ushort_t u; } v;
    v.h = h;
    return v.u;
}

__device__ __forceinline__ uint_t pack2bf(float lo, float hi) {
    return (uint_t)f2bf(lo) | ((uint_t)f2bf(hi) << 16);
}

// tanh(x) = 1 - 2/(e^2x + 1); exp saturation gives exact +-1 tails, no clamp.
__device__ __forceinline__ float fast_tanh(float x) {
    float e = __expf(2.0f * x);
    return fmaf(-2.0f, __builtin_amdgcn_rcpf(e + 1.0f), 1.0f);
}

// 8 LDS gathers from one uint4 of packed u16 byte-offsets
__device__ __forceinline__ void gather8(const char* accb, uint4 o, short8& af) {
    af[0] = *(const short*)(accb + (o.x & 0xffffu));
    af[1] = *(const short*)(accb + (o.x >> 16));
    af[2] = *(const short*)(accb + (o.y & 0xffffu));
    af[3] = *(const short*)(accb + (o.y >> 16));
    af[4] = *(const short*)(accb + (o.z & 0xffffu));
    af[5] = *(const short*)(accb + (o.z >> 16));
    af[6] = *(const short*)(accb + (o.w & 0xffffu));
    af[7] = *(const short*)(accb + (o.w >> 16));
}

// ---- Pre-pack weights (B-frag order, bias in k=24/k=48 slot) + offsets ----
__global__ __launch_bounds__(256)
void convert_weights(const float* __restrict__ W1, const float* __restrict__ b1,
                     const float* __restrict__ W2, const float* __restrict__ b2,
                     const float* __restrict__ W3, const float* __restrict__ b3,
                     const float* __restrict__ Wo, const float* __restrict__ bo,
                     const int* __restrict__ idx1, const int* __restrict__ idx2,
                     const int* __restrict__ idx3, const int* __restrict__ idxo,
                     ushort_t* __restrict__ ws)
{
    const int tid = blockIdx.x * 256 + threadIdx.x;
    const int lane = tid & 63;
    const int nn = lane & 15;
    const int quad = lane >> 4;
    if (tid < 12288) {
        const int g = (tid >> 6) & 63;
        const int l = tid >> 12;   // 0..2
        const float* W = (l == 0) ? W1 : (l == 1) ? W2 : W3;
        const float* bb = (l == 0) ? b1 : (l == 1) ? b2 : b3;
        const float* Wg = W + g * 384;
        ushort_t v[8];
        #pragma unroll
        for (int j = 0; j < 8; ++j) {
            const int k = quad * 8 + j;
            v[j] = (k < 24) ? f2bf(Wg[k * 16 + nn])
                 : (k == 24) ? f2bf(bb[g * 16 + nn]) : (ushort_t)0;
        }
        ushort4* dst = reinterpret_cast<ushort4*>(ws + (size_t)tid * 8);
        dst[0] = make_ushort4(v[0], v[1], v[2], v[3]);
        dst[1] = make_ushort4(v[4], v[5], v[6], v[7]);
    } else if (tid < 12800) {
        const int h = tid - 12288;
        const int gs = h >> 6;          // 0..7: go*2+step
        const int go = gs >> 1;
        const int step = gs & 1;
        const float* Wg = Wo + go * 768;
        ushort_t v[8];
        #pragma unroll
        for (int j = 0; j < 8; ++j) {
            const int k = step * 32 + quad * 8 + j;
            v[j] = (k < 48) ? f2bf(Wg[k * 16 + nn])
                 : (k == 48) ? f2bf(bo[go * 16 + nn]) : (ushort_t)0;
        }
        ushort4* dst = reinterpret_cast<ushort4*>(ws + (size_t)tid * 8);
        dst[0] = make_ushort4(v[0], v[1], v[2], v[3]);
        dst[1] = make_ushort4(v[4], v[5], v[6], v[7]);
    } else if (tid < 18944) {
        // hidden gather byte-offsets (u16), frag order: e = l*2048 + g*32 + k
        const int e = tid - 12800;
        const int l = e >> 11;
        const int rem = e & 2047;
        const int g = rem >> 5;
        const int k = rem & 31;
        const int* idx = (l == 0) ? idx1 : (l == 1) ? idx2 : idx3;
        const int v = (k < 24) ? idx[g * 24 + k] * 2
                    : (k == 24) ? ONE_BYTE : ZERO_BYTE;
        reinterpret_cast<ushort_t*>((char*)ws + OFF_HIDO_B)[e] = (ushort_t)v;
    } else if (tid < 19200) {
        // head gather byte-offsets (u16): e = go*64 + k
        const int e = tid - 18944;
        const int go = e >> 6;
        const int k = e & 63;
        const int v = (k < 48) ? idxo[go * 48 + k] * 2
                    : (k == 48) ? ONE_BYTE : ZERO_BYTE;
        reinterpret_cast<ushort_t*>((char*)ws + OFF_HEADO_B)[e] = (ushort_t)v;
    }
}

#define NTILES 4   // 16384 rows / 16 per tile / 256 blocks

__global__ __launch_bounds__(1024)
void demodel_mfma(const float* __restrict__ x,
                  const ushort_t* __restrict__ ws,
                  float* __restrict__ out)
{
    extern __shared__ __align__(16) ushort_t smem[];
    const int t = threadIdx.x;
    const int lane = t & 63;
    const int wv = t >> 6;               // wave 0..15
    const int nn = lane & 15;
    const int quad = lane >> 4;

    // ---- stage packed u16 offset tables: 12800 B global -> LDS ----
    {
        const uint4* src = reinterpret_cast<const uint4*>((const char*)ws + OFF_HIDO_B);
        uint4* dst = reinterpret_cast<uint4*>(smem + ACC_U16);
        for (int i = t; i < (OFFS_U16 * 2) / 16; i += 1024)   // 800 uint4
            dst[i] = src[i];
    }
    // pad cols per row: [3584]=1.0 (bias slot), [3585..3587]=0  (8 B)
    if (t < 16) {
        uint2* p = reinterpret_cast<uint2*>((char*)smem + t * ROW_BYTES + ONE_BYTE);
        *p = make_uint2(0x00003f80u, 0u);
    }

    const ushort_t* offsu = smem + ACC_U16;                  // u16 table
    const char* accb = (const char*)smem + nn * ROW_BYTES;   // lane's row nn
    char* accw = (char*)smem;

    // prefetch regs for the x tile (waves 8..15: 512 thr x 16 floats)
    const int pr = (t - 512) >> 5;        // row 0..15 (valid for wv>=8)
    const int pc = (t & 31) << 4;         // float col 0..496
    uint_t px[8];

    // ---- prefetch tile 0 ----
    if (wv >= 8) {
        const float4* src = reinterpret_cast<const float4*>(
            x + ((size_t)blockIdx.x * 16 + pr) * 512 + pc);
        float4 a0 = src[0], a1 = src[1], a2 = src[2], a3 = src[3];
        px[0] = pack2bf(a0.x, a0.y); px[1] = pack2bf(a0.z, a0.w);
        px[2] = pack2bf(a1.x, a1.y); px[3] = pack2bf(a1.z, a1.w);
        px[4] = pack2bf(a2.x, a2.y); px[5] = pack2bf(a2.z, a2.w);
        px[6] = pack2bf(a3.x, a3.y); px[7] = pack2bf(a3.z, a3.w);
    }

    #pragma unroll 1
    for (int it = 0; it < NTILES; ++it) {
        const int row0 = (it * 256 + blockIdx.x) * 16;

        __syncthreads();   // prev tile's head gathers done -> x region free
        if (wv >= 8) {     // dump prefetched x: 16 u16 = 32 B as 4x b64
            uint2* d = reinterpret_cast<uint2*>(accw + pr * ROW_BYTES + pc * 2);
            d[0] = make_uint2(px[0], px[1]);
            d[1] = make_uint2(px[2], px[3]);
            d[2] = make_uint2(px[4], px[5]);
            d[3] = make_uint2(px[6], px[7]);
        }
        __syncthreads();

        // ---- 3 hidden layers ----
        #pragma unroll 1
        for (int l = 0; l < 3; ++l) {
            const int out_base = 512 + l * 1024;
            const int g0 = wv << 2;

            uint4 ofs[4];
            short8 bfr[4];
            #pragma unroll
            for (int gi = 0; gi < 4; ++gi) {
                ofs[gi] = *reinterpret_cast<const uint4*>(
                    offsu + l * 2048 + (g0 + gi) * 32 + quad * 8);
                bfr[gi] = *reinterpret_cast<const short8*>(
                    ws + (((size_t)l * 64 + g0 + gi) * 64 + lane) * 8);
            }

            short8 af[4];
            #pragma unroll
            for (int gi = 0; gi < 4; ++gi)
                gather8(accb, ofs[gi], af[gi]);

            f32x4 acc[4];
            #pragma unroll
            for (int gi = 0; gi < 4; ++gi) {
                f32x4 z = { 0.f, 0.f, 0.f, 0.f };
                // swapped: D = W^T * acc^T; lane holds 4 consecutive
                // features (quad*4+i) of its own batch row nn
                acc[gi] = __builtin_amdgcn_mfma_f32_16x16x32_bf16(bfr[gi], af[gi], z, 0, 0, 0);
            }

            #pragma unroll
            for (int gi = 0; gi < 4; ++gi) {
                const int colo = out_base + (g0 + gi) * 16 + quad * 4;
                uint2 w = make_uint2(
                    pack2bf(fast_tanh(acc[gi][0]), fast_tanh(acc[gi][1])),
                    pack2bf(fast_tanh(acc[gi][2]), fast_tanh(acc[gi][3])));
                *reinterpret_cast<uint2*>(accw + nn * ROW_BYTES + colo * 2) = w;
            }
            __syncthreads();
        }

        // ---- head (waves 0..3) and next-x prefetch (waves 8..15) ----
        if (wv < 4) {
            const int go = wv;
            uint4 ofs[2];
            short8 bfr[2];
            #pragma unroll
            for (int s = 0; s < 2; ++s) {
                ofs[s] = *reinterpret_cast<const uint4*>(
                    offsu + 6144 + go * 64 + s * 32 + quad * 8);
                bfr[s] = *reinterpret_cast<const short8*>(
                    ws + (12288 + ((size_t)go * 2 + s) * 64 + lane) * 8);
            }
            short8 af[2];
            #pragma unroll
            for (int s = 0; s < 2; ++s)
                gather8(accb, ofs[s], af[s]);
            f32x4 z = { 0.f, 0.f, 0.f, 0.f };
            f32x4 a0 = __builtin_amdgcn_mfma_f32_16x16x32_bf16(bfr[0], af[0], z, 0, 0, 0);
            f32x4 a1 = __builtin_amdgcn_mfma_f32_16x16x32_bf16(bfr[1], af[1], z, 0, 0, 0);
            // lane holds out[row0+nn][go*16 + quad*4 .. +3] -> one dwordx4
            float4 o;
            o.x = a0[0] + a1[0];
            o.y = a0[1] + a1[1];
            o.z = a0[2] + a1[2];
            o.w = a0[3] + a1[3];
            *reinterpret_cast<float4*>(
                out + (size_t)(row0 + nn) * 64 + go * 16 + quad * 4) = o;
        }
        if (wv >= 8 && it + 1 < NTILES) {
            const float4* src = reinterpret_cast<const float4*>(
                x + (((size_t)(it + 1) * 256 + blockIdx.x) * 16 + pr) * 512 + pc);
            float4 a0 = src[0], a1 = src[1], a2 = src[2], a3 = src[3];
            px[0] = pack2bf(a0.x, a0.y); px[1] = pack2bf(a0.z, a0.w);
            px[2] = pack2bf(a1.x, a1.y); px[3] = pack2bf(a1.z, a1.w);
            px[4] = pack2bf(a2.x, a2.y); px[5] = pack2bf(a2.z, a2.w);
            px[6] = pack2bf(a3.x, a3.y); px[7] = pack2bf(a3.z, a3.w);
        }
    }
}

extern "C" void kernel_launch(void* const* d_in, const int* in_sizes, int n_in,
                              void* d_out, int out_size, void* d_ws, size_t ws_size,
                              hipStream_t stream) {
    const float* x  = (const float*)d_in[0];
    const float* W1 = (const float*)d_in[1];
    const float* b1 = (const float*)d_in[2];
    const float* W2 = (const float*)d_in[3];
    const float* b2 = (const float*)d_in[4];
    const float* W3 = (const float*)d_in[5];
    const float* b3 = (const float*)d_in[6];
    const float* Wo = (const float*)d_in[7];
    const float* bo = (const float*)d_in[8];
    const int* idx1 = (const int*)d_in[9];
    const int* idx2 = (const int*)d_in[10];
    const int* idx3 = (const int*)d_in[11];
    const int* idxo = (const int*)d_in[12];
    float* out = (float*)d_out;

    (void)hipFuncSetAttribute((const void*)demodel_mfma,
                              hipFuncAttributeMaxDynamicSharedMemorySize,
                              LDS_BYTES);

    convert_weights<<<75, 256, 0, stream>>>(W1, b1, W2, b2, W3, b3, Wo, bo,
                                            idx1, idx2, idx3, idxo,
                                            (ushort_t*)d_ws);

    demodel_mfma<<<256, 1024, LDS_BYTES, stream>>>(
        x, (const ushort_t*)d_ws, out);
}